// Round 1
// baseline (1957.977 us; speedup 1.0000x reference)
//
#include <hip/hip_runtime.h>
#include <math.h>

// Problem constants (fixed by reference setup_inputs)
#define BB 4
#define QQ 75
#define CC 640
#define HW 100       // h*w
#define NWAY 5
#define KSHOT 5
#define MS 500       // K_SHOT*HW (support descriptors per way)
#define MSP 512      // padded
#define TEMPER 2.0f
#define EPSN 1e-8f

// ---------------- Kernel 1: normalize + repack support ----------------
// support_xf: (b, 25, c, 100) -> snre: (b, way, c, 512) normalized over c,
// n = shot*100 + p, cols [500,512) zeroed.
__global__ void norm_support(const float* __restrict__ sup, float* __restrict__ snre) {
    int bid = blockIdx.x;              // b*25 + s
    int b = bid / 25, s = bid % 25;
    int w = s / KSHOT, shot = s % KSHOT;
    const float* src = sup + (size_t)bid * CC * HW;
    float* dst = snre + ((size_t)(b * NWAY + w)) * CC * MSP + shot * HW;
    __shared__ float inv[HW];
    int t = threadIdx.x;
    if (t < HW) {
        float ss = 0.f;
        for (int c = 0; c < CC; ++c) { float v = src[c * HW + t]; ss += v * v; }
        inv[t] = 1.f / (sqrtf(ss) + EPSN);
    }
    __syncthreads();
    for (int i = t; i < CC * HW; i += 256) {
        int c = i / HW, p = i % HW;
        dst[c * MSP + p] = src[i] * inv[p];
    }
    if (shot == KSHOT - 1) {  // one block per (b,w) zeroes the pad columns
        float* padbase = snre + ((size_t)(b * NWAY + w)) * CC * MSP;
        for (int i = t; i < CC * (MSP - MS); i += 256) {
            int c = i / (MSP - MS), j = i % (MSP - MS);
            padbase[c * MSP + MS + j] = 0.f;
        }
    }
}

// ---------------- Kernel 2: query inverse norms ----------------
__global__ void qnorm(const float* __restrict__ q, float* __restrict__ invq) {
    int bq = blockIdx.x;
    const float* src = q + (size_t)bq * CC * HW;
    int t = threadIdx.x;
    if (t < HW) {
        float ss = 0.f;
        for (int c = 0; c < CC; ++c) { float v = src[c * HW + t]; ss += v * v; }
        invq[bq * HW + t] = 1.f / (sqrtf(ss) + EPSN);
    }
}

// ---------------- Kernel 3: fused GEMM + per-way max/argmax ----------------
// One block per (bq, w). C-tile: 128 m-rows (100 real) x 64 n-cols per chunk,
// 8 chunks cover n in [0,512) (500 real). K = 640 in steps of 8.
__global__ __launch_bounds__(256) void simkernel(
        const float* __restrict__ q, const float* __restrict__ invq,
        const float* __restrict__ snre,
        float* __restrict__ smax_out, int* __restrict__ sidx_out) {
    int bid = blockIdx.x;                 // bq*5 + w
    int bq = bid / NWAY, w = bid % NWAY;
    int b = bq / QQ;
    const float* gq = q + (size_t)bq * CC * HW;
    const float* gb = snre + ((size_t)(b * NWAY + w)) * CC * MSP;

    __shared__ alignas(16) float As[8][128];
    __shared__ alignas(16) float Bs[8][64];
    __shared__ alignas(16) float4 invq4[32];

    int tid = threadIdx.x;
    if (tid < 32) {
        float4 v;
        int m = tid * 4;
        v.x = (m + 0 < HW) ? invq[bq * HW + m + 0] : 0.f;
        v.y = (m + 1 < HW) ? invq[bq * HW + m + 1] : 0.f;
        v.z = (m + 2 < HW) ? invq[bq * HW + m + 2] : 0.f;
        v.w = (m + 3 < HW) ? invq[bq * HW + m + 3] : 0.f;
        invq4[tid] = v;
    }
    __syncthreads();

    int tx = tid & 15, ty = tid >> 4;
    int akk = tid >> 5;            // 0..7
    int amq = (tid & 31) * 4;      // 0..124
    int bkk = tid >> 5;
    int bnn = (tid & 31) * 2;

    float rmax[8];
    int ridx[8];
#pragma unroll
    for (int r = 0; r < 8; ++r) { rmax[r] = -INFINITY; ridx[r] = 0; }

    for (int nc = 0; nc < 8; ++nc) {
        int n0 = nc * 64;
        float acc[2][4][4];
#pragma unroll
        for (int s = 0; s < 2; ++s)
#pragma unroll
            for (int i = 0; i < 4; ++i)
#pragma unroll
                for (int j = 0; j < 4; ++j) acc[s][i][j] = 0.f;

        for (int c0 = 0; c0 < CC; c0 += 8) {
            // global loads to registers
            float4 av;
            if (amq < HW) {
                av = *(const float4*)(gq + (size_t)(c0 + akk) * HW + amq);
                float4 iv = invq4[amq >> 2];
                av.x *= iv.x; av.y *= iv.y; av.z *= iv.z; av.w *= iv.w;
            } else {
                av = make_float4(0.f, 0.f, 0.f, 0.f);
            }
            float2 bv = *(const float2*)(gb + (size_t)(c0 + bkk) * MSP + n0 + bnn);

            __syncthreads();   // previous compute done reading LDS
            *(float4*)(&As[akk][amq]) = av;
            *(float2*)(&Bs[bkk][bnn]) = bv;
            __syncthreads();

#pragma unroll
            for (int kk = 0; kk < 8; ++kk) {
                float4 b4 = *(const float4*)(&Bs[kk][tx * 4]);
                float4 a0 = *(const float4*)(&As[kk][ty * 4]);
                float4 a1 = *(const float4*)(&As[kk][64 + ty * 4]);
                float bbv[4] = {b4.x, b4.y, b4.z, b4.w};
                float aav[2][4] = {{a0.x, a0.y, a0.z, a0.w},
                                   {a1.x, a1.y, a1.z, a1.w}};
#pragma unroll
                for (int s = 0; s < 2; ++s)
#pragma unroll
                    for (int i = 0; i < 4; ++i)
#pragma unroll
                        for (int j = 0; j < 4; ++j)
                            acc[s][i][j] = fmaf(aav[s][i], bbv[j], acc[s][i][j]);
            }
        }

        // fused reduction of this 64-col chunk: per-row max + first-occurrence argmax
#pragma unroll
        for (int r = 0; r < 8; ++r) {
            float v = -INFINITY; int idx = 0;
#pragma unroll
            for (int j = 0; j < 4; ++j) {
                int n = n0 + tx * 4 + j;
                float cv = acc[r >> 2][r & 3][j];
                if (n < MS && cv > v) { v = cv; idx = n; }
            }
#pragma unroll
            for (int mshift = 1; mshift < 16; mshift <<= 1) {
                float ov = __shfl_xor(v, mshift);
                int oi = __shfl_xor(idx, mshift);
                if (ov > v || (ov == v && oi < idx)) { v = ov; idx = oi; }
            }
            if (v > rmax[r]) { rmax[r] = v; ridx[r] = idx; }  // chunks ascend in n
        }
    }

    if (tx == 0) {
#pragma unroll
        for (int r = 0; r < 8; ++r) {
            int mrow = (r < 4) ? (ty * 4 + r) : (64 + ty * 4 + (r - 4));
            if (mrow < HW) {
                smax_out[(size_t)bid * HW + mrow] = rmax[r];
                sidx_out[(size_t)bid * HW + mrow] = ridx[r];
            }
        }
    }
}

// ---------------- Kernel 4: top-2 diff, nearest, mutual mask, predict, NLL ----------------
__global__ void finalize(const float* __restrict__ smax, const int* __restrict__ sidx,
                         const int* __restrict__ qy, float* __restrict__ lossi) {
    int bq = blockIdx.x;
    __shared__ float sm[NWAY][HW];
    __shared__ int   si[NWAY][HW];
    __shared__ float diffv[HW];
    __shared__ int   nearest[HW];
    __shared__ float maskv[HW];
    __shared__ float pred[NWAY];
    int t = threadIdx.x;
    for (int i = t; i < NWAY * HW; i += blockDim.x) {
        sm[i / HW][i % HW] = smax[(size_t)bq * NWAY * HW + i];
        si[i / HW][i % HW] = sidx[(size_t)bq * NWAY * HW + i];
    }
    __syncthreads();
    if (t < HW) {
        float v1 = -INFINITY, v2 = -INFINITY;
        float bestv = -INFINITY; int bestslot = 0;
        for (int w = 0; w < NWAY; ++w) {
            float v = sm[w][t];
            if (v > v1) { v2 = v1; v1 = v; } else if (v > v2) { v2 = v; }
            if (v > bestv) { bestv = v; bestslot = w * MS + si[w][t]; }  // w-major first occurrence
        }
        diffv[t] = v1 - v2;
        nearest[t] = bestslot;
    }
    __syncthreads();
    if (t < HW) {
        // argmax over m' of (nearest[m']==slot ? diff[m'] : 0), first occurrence
        int slot = nearest[t];
        float bv = (nearest[0] == slot) ? diffv[0] : 0.f;
        int bm = 0;
        for (int m = 1; m < HW; ++m) {
            float val = (nearest[m] == slot) ? diffv[m] : 0.f;
            if (val > bv) { bv = val; bm = m; }
        }
        maskv[t] = (bm == t) ? TEMPER : 0.f;
    }
    __syncthreads();
    if (t < NWAY) {
        float s = 0.f;
        for (int m = 0; m < HW; ++m) s += sm[t][m] * maskv[m];
        pred[t] = s;
    }
    __syncthreads();
    if (t == 0) {
        float mx = pred[0];
        for (int w = 1; w < NWAY; ++w) mx = fmaxf(mx, pred[w]);
        float se = 0.f;
        for (int w = 0; w < NWAY; ++w) se += expf(pred[w] - mx);
        float lse = mx + logf(se);
        int y = qy[bq];
        lossi[bq] = -(pred[y] - lse);
    }
}

// ---------------- Kernel 5: mean ----------------
__global__ void reduce_loss(const float* __restrict__ lossi, float* __restrict__ out) {
    int t = threadIdx.x;  // 64 threads
    float v = 0.f;
    for (int i = t; i < BB * QQ; i += 64) v += lossi[i];
    for (int m = 32; m > 0; m >>= 1) v += __shfl_xor(v, m);
    if (t == 0) out[0] = v / (float)(BB * QQ);
}

extern "C" void kernel_launch(void* const* d_in, const int* in_sizes, int n_in,
                              void* d_out, int out_size, void* d_ws, size_t ws_size,
                              hipStream_t stream) {
    const float* sup = (const float*)d_in[0];   // support_xf (4,25,640,10,10) f32
    const float* qx  = (const float*)d_in[2];   // query_xf   (4,75,640,10,10) f32
    const int*   qy  = (const int*)d_in[3];     // query_y    (4,75) int32
    float* out = (float*)d_out;

    // workspace layout (~27.6 MB total)
    float* snre = (float*)d_ws;                             // 4*5*640*512 = 6,553,600 f
    float* invq = snre + (size_t)BB * NWAY * CC * MSP;      // 30,000 f
    float* smax = invq + (size_t)BB * QQ * HW;              // 150,000 f
    int*   sidx = (int*)(smax + (size_t)BB * QQ * NWAY * HW); // 150,000 i
    float* lossi = (float*)(sidx + (size_t)BB * QQ * NWAY * HW); // 300 f

    hipLaunchKernelGGL(norm_support, dim3(BB * 25), dim3(256), 0, stream, sup, snre);
    hipLaunchKernelGGL(qnorm, dim3(BB * QQ), dim3(128), 0, stream, qx, invq);
    hipLaunchKernelGGL(simkernel, dim3(BB * QQ * NWAY), dim3(256), 0, stream,
                       qx, invq, snre, smax, sidx);
    hipLaunchKernelGGL(finalize, dim3(BB * QQ), dim3(128), 0, stream, smax, sidx, qy, lossi);
    hipLaunchKernelGGL(reduce_loss, dim3(1), dim3(64), 0, stream, lossi, out);
}

// Round 2
// 1429.840 us; speedup vs baseline: 1.3694x; 1.3694x over previous
//
#include <hip/hip_runtime.h>
#include <math.h>

// Problem constants (fixed by reference setup_inputs)
#define BB 4
#define QQ 75
#define CC 640
#define HW 100       // h*w
#define NWAY 5
#define KSHOT 5
#define MS 500       // K_SHOT*HW (support descriptors per way)
#define MSP 512      // padded
#define MTOT 7500    // QQ*HW query descriptors per batch
#define MT 59        // ceil(7500/128)
#define TEMPER 2.0f
#define EPSN 1e-8f

// ---------------- Kernel 1: normalize + repack support ----------------
__global__ void norm_support(const float* __restrict__ sup, float* __restrict__ snre) {
    int bid = blockIdx.x;              // b*25 + s
    int b = bid / 25, s = bid % 25;
    int w = s / KSHOT, shot = s % KSHOT;
    const float* src = sup + (size_t)bid * CC * HW;
    float* dst = snre + ((size_t)(b * NWAY + w)) * CC * MSP + shot * HW;
    __shared__ float inv[HW];
    int t = threadIdx.x;
    if (t < HW) {
        float ss = 0.f;
        for (int c = 0; c < CC; ++c) { float v = src[c * HW + t]; ss += v * v; }
        inv[t] = 1.f / (sqrtf(ss) + EPSN);
    }
    __syncthreads();
    for (int i = t; i < CC * HW; i += 256) {
        int c = i / HW, p = i % HW;
        dst[c * MSP + p] = src[i] * inv[p];
    }
    if (shot == KSHOT - 1) {  // one block per (b,w) zeroes the pad columns
        float* padbase = snre + ((size_t)(b * NWAY + w)) * CC * MSP;
        for (int i = t; i < CC * (MSP - MS); i += 256) {
            int c = i / (MSP - MS), j = i % (MSP - MS);
            padbase[c * MSP + MS + j] = 0.f;
        }
    }
}

// ---------------- Kernel 2: query inverse norms ----------------
__global__ void qnorm(const float* __restrict__ q, float* __restrict__ invq) {
    int bq = blockIdx.x;
    const float* src = q + (size_t)bq * CC * HW;
    int t = threadIdx.x;
    if (t < HW) {
        float ss = 0.f;
        for (int c = 0; c < CC; ++c) { float v = src[c * HW + t]; ss += v * v; }
        invq[bq * HW + t] = 1.f / (sqrtf(ss) + EPSN);
    }
}

// ---------------- Kernel 3: raw-dot GEMM + per-chunk max/argmax ----------------
// Grid: bid = ((b*MT + mt)*NWAY + w)*8 + nc. Tile: 128 m-rows x 64 n-cols,
// K=640 in steps of 8, double-buffered LDS, one barrier per step.
// A is UNNORMALIZED query data (invq applied in combine); m spans all 75
// queries of batch b (m = q*100 + p; float4 never crosses query boundary
// since 100 % 4 == 0).
__global__ __launch_bounds__(256) void simkernel(
        const float* __restrict__ qx, const float* __restrict__ snre,
        float* __restrict__ pmax, int* __restrict__ pidx) {
    int bid = blockIdx.x;
    int nc = bid & 7;
    int t1 = bid >> 3;
    int w = t1 % NWAY; t1 /= NWAY;
    int mt = t1 % MT;  int b = t1 / MT;
    int m0 = mt * 128, n0 = nc * 64;

    __shared__ alignas(16) float As[2][8][128];
    __shared__ alignas(16) float Bs[2][8][64];

    int tid = threadIdx.x;
    int kk = tid >> 5;            // staging k-row 0..7
    int mloc = (tid & 31) * 4;    // staging m offset (float4)
    int nloc2 = (tid & 31) * 2;   // staging n offset (float2)

    int m_g = m0 + mloc;
    int qi = 0, p = 0;
    if (m_g < MTOT) { qi = m_g / HW; p = m_g % HW; }   // clamp pad rows to (0,0)
    const float* gA = qx + ((size_t)(b * QQ + qi) * CC + kk) * HW + p;
    const float* gB = snre + ((size_t)(b * NWAY + w) * CC + kk) * MSP + n0 + nloc2;

    int tx = tid & 15, ty = tid >> 4;

    float acc[2][4][4];
#pragma unroll
    for (int s = 0; s < 2; ++s)
#pragma unroll
        for (int i = 0; i < 4; ++i)
#pragma unroll
            for (int j = 0; j < 4; ++j) acc[s][i][j] = 0.f;

    // prologue: stage c0 = 0 into buffer 0
    float4 av = *(const float4*)gA;
    float2 bv = *(const float2*)gB;
    *(float4*)&As[0][kk][mloc] = av;
    *(float2*)&Bs[0][kk][nloc2] = bv;
    __syncthreads();

    for (int s = 0; s < 80; ++s) {
        int cur = s & 1;
        if (s < 79) {               // issue next-tile global loads early
            gA += 8 * HW;
            gB += 8 * MSP;
            av = *(const float4*)gA;
            bv = *(const float2*)gB;
        }
#pragma unroll
        for (int k2 = 0; k2 < 8; ++k2) {
            float4 b4 = *(const float4*)&Bs[cur][k2][tx * 4];
            float4 a0 = *(const float4*)&As[cur][k2][ty * 4];
            float4 a1 = *(const float4*)&As[cur][k2][64 + ty * 4];
            float bbv[4] = {b4.x, b4.y, b4.z, b4.w};
            float aav[2][4] = {{a0.x, a0.y, a0.z, a0.w},
                               {a1.x, a1.y, a1.z, a1.w}};
#pragma unroll
            for (int sg = 0; sg < 2; ++sg)
#pragma unroll
                for (int i = 0; i < 4; ++i)
#pragma unroll
                    for (int j = 0; j < 4; ++j)
                        acc[sg][i][j] = fmaf(aav[sg][i], bbv[j], acc[sg][i][j]);
        }
        if (s < 79) {               // write next tile into the other buffer
            *(float4*)&As[cur ^ 1][kk][mloc] = av;
            *(float2*)&Bs[cur ^ 1][kk][nloc2] = bv;
        }
        __syncthreads();
    }

    // per-row max + first-occurrence argmax over this 64-col chunk
#pragma unroll
    for (int r = 0; r < 8; ++r) {
        float v = -INFINITY; int idx = 0;
#pragma unroll
        for (int j = 0; j < 4; ++j) {
            int n = n0 + tx * 4 + j;
            float cv = acc[r >> 2][r & 3][j];
            if (n < MS && cv > v) { v = cv; idx = n; }
        }
#pragma unroll
        for (int msk = 1; msk < 16; msk <<= 1) {
            float ov = __shfl_xor(v, msk);
            int oi = __shfl_xor(idx, msk);
            if (ov > v || (ov == v && oi < idx)) { v = ov; idx = oi; }
        }
        if (tx == 0) {
            int mrow = (r >> 2) * 64 + ty * 4 + (r & 3);
            pmax[(size_t)bid * 128 + mrow] = v;
            pidx[(size_t)bid * 128 + mrow] = idx;
        }
    }
}

// ---------------- Kernel 3b: combine 8 n-chunks, apply invq ----------------
__global__ void combine(const float* __restrict__ pmax, const int* __restrict__ pidx,
                        const float* __restrict__ invq,
                        float* __restrict__ smax, int* __restrict__ sidx) {
    int g = blockIdx.x * 256 + threadIdx.x;     // over BB*NWAY*MTOT
    if (g >= BB * NWAY * MTOT) return;
    int m = g % MTOT; int t = g / MTOT;
    int w = t % NWAY, b = t / NWAY;
    int mt = m / 128, mrow = m % 128;
    size_t base = (((size_t)(b * MT + mt) * NWAY + w) * 8) * 128 + mrow;
    float best = pmax[base]; int bi = pidx[base];
#pragma unroll
    for (int ncc = 1; ncc < 8; ++ncc) {
        float v = pmax[base + (size_t)ncc * 128];
        int ii = pidx[base + (size_t)ncc * 128];
        if (v > best) { best = v; bi = ii; }    // chunks ascend in n: strict > keeps first
    }
    int qi2 = m / HW, p2 = m % HW;
    size_t o = ((size_t)(b * QQ + qi2) * NWAY + w) * HW + p2;
    smax[o] = best * invq[b * MTOT + m];
    sidx[o] = bi;
}

// ---------------- Kernel 4: top-2 diff, nearest, mutual mask, predict, NLL ----------------
__global__ void finalize(const float* __restrict__ smax, const int* __restrict__ sidx,
                         const int* __restrict__ qy, float* __restrict__ lossi) {
    int bq = blockIdx.x;
    __shared__ float sm[NWAY][HW];
    __shared__ int   si[NWAY][HW];
    __shared__ float diffv[HW];
    __shared__ int   nearest[HW];
    __shared__ float maskv[HW];
    __shared__ float pred[NWAY];
    int t = threadIdx.x;
    for (int i = t; i < NWAY * HW; i += blockDim.x) {
        sm[i / HW][i % HW] = smax[(size_t)bq * NWAY * HW + i];
        si[i / HW][i % HW] = sidx[(size_t)bq * NWAY * HW + i];
    }
    __syncthreads();
    if (t < HW) {
        float v1 = -INFINITY, v2 = -INFINITY;
        float bestv = -INFINITY; int bestslot = 0;
        for (int w = 0; w < NWAY; ++w) {
            float v = sm[w][t];
            if (v > v1) { v2 = v1; v1 = v; } else if (v > v2) { v2 = v; }
            if (v > bestv) { bestv = v; bestslot = w * MS + si[w][t]; }
        }
        diffv[t] = v1 - v2;
        nearest[t] = bestslot;
    }
    __syncthreads();
    if (t < HW) {
        int slot = nearest[t];
        float bv = (nearest[0] == slot) ? diffv[0] : 0.f;
        int bm = 0;
        for (int m = 1; m < HW; ++m) {
            float val = (nearest[m] == slot) ? diffv[m] : 0.f;
            if (val > bv) { bv = val; bm = m; }
        }
        maskv[t] = (bm == t) ? TEMPER : 0.f;
    }
    __syncthreads();
    if (t < NWAY) {
        float s = 0.f;
        for (int m = 0; m < HW; ++m) s += sm[t][m] * maskv[m];
        pred[t] = s;
    }
    __syncthreads();
    if (t == 0) {
        float mx = pred[0];
        for (int w = 1; w < NWAY; ++w) mx = fmaxf(mx, pred[w]);
        float se = 0.f;
        for (int w = 0; w < NWAY; ++w) se += expf(pred[w] - mx);
        float lse = mx + logf(se);
        int y = qy[bq];
        lossi[bq] = -(pred[y] - lse);
    }
}

// ---------------- Kernel 5: mean ----------------
__global__ void reduce_loss(const float* __restrict__ lossi, float* __restrict__ out) {
    int t = threadIdx.x;  // 64 threads
    float v = 0.f;
    for (int i = t; i < BB * QQ; i += 64) v += lossi[i];
    for (int m = 32; m > 0; m >>= 1) v += __shfl_xor(v, m);
    if (t == 0) out[0] = v / (float)(BB * QQ);
}

extern "C" void kernel_launch(void* const* d_in, const int* in_sizes, int n_in,
                              void* d_out, int out_size, void* d_ws, size_t ws_size,
                              hipStream_t stream) {
    const float* sup = (const float*)d_in[0];   // support_xf (4,25,640,10,10) f32
    const float* qx  = (const float*)d_in[2];   // query_xf   (4,75,640,10,10) f32
    const int*   qy  = (const int*)d_in[3];     // query_y    (4,75) int32
    float* out = (float*)d_out;

    // workspace layout (~37.2 MB total)
    float* snre = (float*)d_ws;                               // 4*5*640*512 = 6,553,600 f
    float* invq = snre + (size_t)BB * NWAY * CC * MSP;        // 30,000 f
    float* pmax = invq + (size_t)BB * MTOT;                   // 9440*128 f
    int*   pidx = (int*)(pmax + (size_t)BB * MT * NWAY * 8 * 128);
    float* smax = (float*)(pidx + (size_t)BB * MT * NWAY * 8 * 128);  // 150,000 f
    int*   sidx = (int*)(smax + (size_t)BB * QQ * NWAY * HW);         // 150,000 i
    float* lossi = (float*)(sidx + (size_t)BB * QQ * NWAY * HW);      // 300 f

    hipLaunchKernelGGL(norm_support, dim3(BB * 25), dim3(256), 0, stream, sup, snre);
    hipLaunchKernelGGL(qnorm, dim3(BB * QQ), dim3(128), 0, stream, qx, invq);
    hipLaunchKernelGGL(simkernel, dim3(BB * MT * NWAY * 8), dim3(256), 0, stream,
                       qx, snre, pmax, pidx);
    hipLaunchKernelGGL(combine, dim3((BB * NWAY * MTOT + 255) / 256), dim3(256), 0, stream,
                       pmax, pidx, invq, smax, sidx);
    hipLaunchKernelGGL(finalize, dim3(BB * QQ), dim3(128), 0, stream, smax, sidx, qy, lossi);
    hipLaunchKernelGGL(reduce_loss, dim3(1), dim3(64), 0, stream, lossi, out);
}

// Round 3
// 840.475 us; speedup vs baseline: 2.3296x; 1.7012x over previous
//
#include <hip/hip_runtime.h>
#include <math.h>

#define BB 4
#define QQ 75
#define CC 640
#define HW 100
#define NWAY 5
#define KSHOT 5
#define MS 500
#define MSP 512
#define MTOT 7500
#define MPAD 7680     // 60 tiles of 128
#define TEMPER 2.0f
#define EPSN 1e-8f

typedef _Float16 v8h __attribute__((ext_vector_type(8)));
typedef float v4f __attribute__((ext_vector_type(4)));

// ---------------- Kernel 1: normalize + repack support (fp32, n-padded 512) --------
__global__ void norm_support(const float* __restrict__ sup, float* __restrict__ snre) {
    int bid = blockIdx.x;              // b*25 + s
    int b = bid / 25, s = bid % 25;
    int w = s / KSHOT, shot = s % KSHOT;
    const float* src = sup + (size_t)bid * CC * HW;
    float* dst = snre + ((size_t)(b * NWAY + w)) * CC * MSP + shot * HW;
    __shared__ float inv[HW];
    int t = threadIdx.x;
    if (t < HW) {
        float ss = 0.f;
        for (int c = 0; c < CC; ++c) { float v = src[c * HW + t]; ss += v * v; }
        inv[t] = 1.f / (sqrtf(ss) + EPSN);
    }
    __syncthreads();
    for (int i = t; i < CC * HW; i += 256) {
        int c = i / HW, p = i % HW;
        dst[c * MSP + p] = src[i] * inv[p];
    }
    if (shot == KSHOT - 1) {
        float* padbase = snre + ((size_t)(b * NWAY + w)) * CC * MSP;
        for (int i = t; i < CC * (MSP - MS); i += 256) {
            int c = i / (MSP - MS), j = i % (MSP - MS);
            padbase[c * MSP + MS + j] = 0.f;
        }
    }
}

// ---------------- Kernel 2: query inverse norms ----------------
__global__ void qnorm(const float* __restrict__ q, float* __restrict__ invq) {
    int bq = blockIdx.x;
    const float* src = q + (size_t)bq * CC * HW;
    int t = threadIdx.x;
    if (t < HW) {
        float ss = 0.f;
        for (int c = 0; c < CC; ++c) { float v = src[c * HW + t]; ss += v * v; }
        invq[bq * HW + t] = 1.f / (sqrtf(ss) + EPSN);
    }
}

__device__ inline void split8(const float* __restrict__ x, v8h& hi, v8h& lo) {
#pragma unroll
    for (int j = 0; j < 8; ++j) {
        _Float16 h = (_Float16)x[j];
        float r = x[j] - (float)h;
        hi[j] = h;
        lo[j] = (_Float16)r;
    }
}

// ---------------- Kernel 3: fp16x3 MFMA GEMM + fused per-128n max/argmax ----------
// Grid: bid = (b*10 + nt)*60 + mt. Block tile 128m x 256n, 4 waves of 64x128.
// K = 640 in 20 chunks of 32. A = raw query (unnormalized; invq applied in combine),
// B = normalized support (snre). S split: hi*hi + hi*lo + lo*hi in f16 MFMA.
__global__ __launch_bounds__(256) void simkernel(
        const float* __restrict__ qx, const float* __restrict__ snre,
        float* __restrict__ pmax, int* __restrict__ pidx) {
    __shared__ char lds_raw[49152];
    v8h* AHI = (v8h*)(lds_raw);                 // 128 m * 4 oct  (8 KB)
    v8h* ALO = (v8h*)(lds_raw + 8192);
    v8h* BHI = (v8h*)(lds_raw + 16384);         // 256 n * 4 oct  (16 KB)
    v8h* BLO = (v8h*)(lds_raw + 32768);

    int bid = blockIdx.x;
    int mt = bid % 60; int t2 = bid / 60;
    int nt = t2 % 10;  int b = t2 / 10;
    int m0 = mt * 128;
    int w = nt >> 1;
    int n0w = (nt & 1) * 256;    // n offset within the way (0 or 256)

    int tid = threadIdx.x;
    const float* Abase = qx + (size_t)b * QQ * CC * HW;
    const float* Bbase = snre + (size_t)(b * NWAY + w) * CC * MSP;

    // staging cell geometry (hoisted): oct = tid&3, row = tid>>2 (+64/+128/+192)
    int oct = tid & 3;
    int arow = tid >> 2;
    // A rows for pass 0/1, with clamp for pad rows
    int aqi[2], ap[2];
#pragma unroll
    for (int pass = 0; pass < 2; ++pass) {
        int mg = m0 + arow + pass * 64;
        if (mg >= MTOT) mg = 0;
        aqi[pass] = mg / HW; ap[pass] = mg % HW;
    }

    v4f acc[4][8];
#pragma unroll
    for (int mf = 0; mf < 4; ++mf)
#pragma unroll
        for (int nf = 0; nf < 8; ++nf) acc[mf][nf] = (v4f)0.f;

    int lane = tid & 63;
    int wv = tid >> 6;
    int mrow_w = (wv >> 1) * 64;
    int ncol_w = (wv & 1) * 128;
    int lq = lane >> 4, lc = lane & 15;

    for (int ch = 0; ch < 20; ++ch) {
        int c0 = ch * 32 + oct * 8;
        __syncthreads();   // previous compute done before overwriting LDS
        // ---- stage A (2 cells/thread) ----
#pragma unroll
        for (int pass = 0; pass < 2; ++pass) {
            const float* src = Abase + ((size_t)aqi[pass] * CC + c0) * HW + ap[pass];
            float x[8];
#pragma unroll
            for (int j = 0; j < 8; ++j) x[j] = src[j * HW];
            v8h hi, lo; split8(x, hi, lo);
            int cell = (arow + pass * 64) * 4 + oct;
            AHI[cell] = hi; ALO[cell] = lo;
        }
        // ---- stage B (4 cells/thread) ----
#pragma unroll
        for (int pass = 0; pass < 4; ++pass) {
            int nrow = arow + pass * 64;          // 0..255
            const float* src = Bbase + (size_t)c0 * MSP + n0w + nrow;
            float x[8];
#pragma unroll
            for (int j = 0; j < 8; ++j) x[j] = src[j * MSP];
            v8h hi, lo; split8(x, hi, lo);
            int cell = nrow * 4 + oct;
            BHI[cell] = hi; BLO[cell] = lo;
        }
        __syncthreads();

        // ---- compute ----
        v8h ahi[4], alo[4];
#pragma unroll
        for (int mf = 0; mf < 4; ++mf) {
            int idx = (mrow_w + mf * 16 + lc) * 4 + lq;
            ahi[mf] = AHI[idx]; alo[mf] = ALO[idx];
        }
#pragma unroll
        for (int nf = 0; nf < 8; ++nf) {
            int idx = (ncol_w + nf * 16 + lc) * 4 + lq;
            v8h bhi = BHI[idx], blo = BLO[idx];
#pragma unroll
            for (int mf = 0; mf < 4; ++mf) {
                acc[mf][nf] = __builtin_amdgcn_mfma_f32_16x16x32_f16(ahi[mf], bhi, acc[mf][nf], 0, 0, 0);
                acc[mf][nf] = __builtin_amdgcn_mfma_f32_16x16x32_f16(ahi[mf], blo, acc[mf][nf], 0, 0, 0);
                acc[mf][nf] = __builtin_amdgcn_mfma_f32_16x16x32_f16(alo[mf], bhi, acc[mf][nf], 0, 0, 0);
            }
        }
    }

    // ---- epilogue: per-row max + first-occurrence argmax over this wave's 128 n ----
    int chunkidx = (nt & 1) * 2 + (wv & 1);    // ascending n within the way
#pragma unroll
    for (int mf = 0; mf < 4; ++mf) {
#pragma unroll
        for (int r = 0; r < 4; ++r) {
            float v = -__builtin_inff(); int idx = 0x7fffffff;
#pragma unroll
            for (int nf = 0; nf < 8; ++nf) {
                int n_way = n0w + ncol_w + nf * 16 + lc;
                float cv = acc[mf][nf][r];
                if (n_way < MS && cv > v) { v = cv; idx = n_way; }
            }
#pragma unroll
            for (int msk = 1; msk < 16; msk <<= 1) {
                float ov = __shfl_xor(v, msk);
                int oi = __shfl_xor(idx, msk);
                if (ov > v || (ov == v && oi < idx)) { v = ov; idx = oi; }
            }
            if (lc == 0) {
                int mrow = m0 + mrow_w + mf * 16 + lq * 4 + r;
                size_t o = ((size_t)(b * NWAY + w) * 4 + chunkidx) * MPAD + mrow;
                pmax[o] = v; pidx[o] = idx;
            }
        }
    }
}

// ---------------- Kernel 3b: combine 4 n-chunks, apply invq ----------------
__global__ void combine(const float* __restrict__ pmax, const int* __restrict__ pidx,
                        const float* __restrict__ invq,
                        float* __restrict__ smax, int* __restrict__ sidx) {
    int g = blockIdx.x * 256 + threadIdx.x;     // over BB*NWAY*MTOT
    if (g >= BB * NWAY * MTOT) return;
    int m = g % MTOT; int t = g / MTOT;
    int w = t % NWAY, b = t / NWAY;
    size_t base = ((size_t)(b * NWAY + w) * 4) * MPAD + m;
    float best = pmax[base]; int bi = pidx[base];
#pragma unroll
    for (int c = 1; c < 4; ++c) {
        float v = pmax[base + (size_t)c * MPAD];
        int ii = pidx[base + (size_t)c * MPAD];
        if (v > best) { best = v; bi = ii; }    // chunks ascend in n: strict > keeps first
    }
    int qi = m / HW, p = m % HW;
    size_t o = ((size_t)(b * QQ + qi) * NWAY + w) * HW + p;
    smax[o] = best * invq[b * MTOT + m];
    sidx[o] = bi;
}

// ---------------- Kernel 4: top-2 diff, nearest, mutual mask, predict, NLL -------
__global__ void finalize(const float* __restrict__ smax, const int* __restrict__ sidx,
                         const int* __restrict__ qy, float* __restrict__ lossi) {
    int bq = blockIdx.x;
    __shared__ float sm[NWAY][HW];
    __shared__ int   si[NWAY][HW];
    __shared__ float diffv[HW];
    __shared__ int   nearest[HW];
    __shared__ float maskv[HW];
    __shared__ float pred[NWAY];
    int t = threadIdx.x;
    for (int i = t; i < NWAY * HW; i += blockDim.x) {
        sm[i / HW][i % HW] = smax[(size_t)bq * NWAY * HW + i];
        si[i / HW][i % HW] = sidx[(size_t)bq * NWAY * HW + i];
    }
    __syncthreads();
    if (t < HW) {
        float v1 = -INFINITY, v2 = -INFINITY;
        float bestv = -INFINITY; int bestslot = 0;
        for (int w = 0; w < NWAY; ++w) {
            float v = sm[w][t];
            if (v > v1) { v2 = v1; v1 = v; } else if (v > v2) { v2 = v; }
            if (v > bestv) { bestv = v; bestslot = w * MS + si[w][t]; }
        }
        diffv[t] = v1 - v2;
        nearest[t] = bestslot;
    }
    __syncthreads();
    if (t < HW) {
        int slot = nearest[t];
        float bv = (nearest[0] == slot) ? diffv[0] : 0.f;
        int bm = 0;
        for (int m = 1; m < HW; ++m) {
            float val = (nearest[m] == slot) ? diffv[m] : 0.f;
            if (val > bv) { bv = val; bm = m; }
        }
        maskv[t] = (bm == t) ? TEMPER : 0.f;
    }
    __syncthreads();
    if (t < NWAY) {
        float s = 0.f;
        for (int m = 0; m < HW; ++m) s += sm[t][m] * maskv[m];
        pred[t] = s;
    }
    __syncthreads();
    if (t == 0) {
        float mx = pred[0];
        for (int w = 1; w < NWAY; ++w) mx = fmaxf(mx, pred[w]);
        float se = 0.f;
        for (int w = 0; w < NWAY; ++w) se += expf(pred[w] - mx);
        float lse = mx + logf(se);
        int y = qy[bq];
        lossi[bq] = -(pred[y] - lse);
    }
}

// ---------------- Kernel 5: mean ----------------
__global__ void reduce_loss(const float* __restrict__ lossi, float* __restrict__ out) {
    int t = threadIdx.x;
    float v = 0.f;
    for (int i = t; i < BB * QQ; i += 64) v += lossi[i];
    for (int m = 32; m > 0; m >>= 1) v += __shfl_xor(v, m);
    if (t == 0) out[0] = v / (float)(BB * QQ);
}

extern "C" void kernel_launch(void* const* d_in, const int* in_sizes, int n_in,
                              void* d_out, int out_size, void* d_ws, size_t ws_size,
                              hipStream_t stream) {
    const float* sup = (const float*)d_in[0];   // support_xf (4,25,640,10,10) f32
    const float* qx  = (const float*)d_in[2];   // query_xf   (4,75,640,10,10) f32
    const int*   qy  = (const int*)d_in[3];     // query_y    (4,75) int32
    float* out = (float*)d_out;

    // workspace (~33 MB)
    float* snre = (float*)d_ws;                               // 4*5*640*512 f
    float* invq = snre + (size_t)BB * NWAY * CC * MSP;        // 30,000 f
    float* pmax = invq + (size_t)BB * MTOT;                   // 4*5*4*7680 f
    int*   pidx = (int*)(pmax + (size_t)BB * NWAY * 4 * MPAD);
    float* smax = (float*)(pidx + (size_t)BB * NWAY * 4 * MPAD);
    int*   sidx = (int*)(smax + (size_t)BB * QQ * NWAY * HW);
    float* lossi = (float*)(sidx + (size_t)BB * QQ * NWAY * HW);

    hipLaunchKernelGGL(norm_support, dim3(BB * 25), dim3(256), 0, stream, sup, snre);
    hipLaunchKernelGGL(qnorm, dim3(BB * QQ), dim3(128), 0, stream, qx, invq);
    hipLaunchKernelGGL(simkernel, dim3(BB * 10 * 60), dim3(256), 0, stream,
                       qx, snre, pmax, pidx);
    hipLaunchKernelGGL(combine, dim3((BB * NWAY * MTOT + 255) / 256), dim3(256), 0, stream,
                       pmax, pidx, invq, smax, sidx);
    hipLaunchKernelGGL(finalize, dim3(BB * QQ), dim3(128), 0, stream, smax, sidx, qy, lossi);
    hipLaunchKernelGGL(reduce_loss, dim3(1), dim3(64), 0, stream, lossi, out);
}